// Round 8
// baseline (340.067 us; speedup 1.0000x reference)
//
#include <hip/hip_runtime.h>
#include <hip/hip_fp16.h>
#include <math.h>

#define ALPHA 0.1f
#define CHUNK 8192

typedef _Float16 f16x8 __attribute__((ext_vector_type(8)));
typedef float f32x4 __attribute__((ext_vector_type(4)));

static __device__ __forceinline__ void nt_store_half(__half* p, float v) {
    __builtin_nontemporal_store((_Float16)v, (_Float16*)p);
}

// ================= bucketed CSR build =================

__global__ void k_zero(int* a, int n) {
    int i = blockIdx.x * blockDim.x + threadIdx.x;
    if (i < n) a[i] = 0;
}

__global__ __launch_bounds__(256) void kb_hist(const int* __restrict__ col, int e,
                                               int nbuck, int* __restrict__ tot) {
    __shared__ int h[1024];
    int t = threadIdx.x;
    for (int i = t; i < 1024; i += 256) h[i] = 0;
    __syncthreads();
    int base = blockIdx.x * CHUNK;
    int end = min(base + CHUNK, e);
    for (int i = base + t; i < end; i += 256)
        atomicAdd(&h[col[i] >> 7], 1);
    __syncthreads();
    for (int i = t; i < nbuck; i += 256)
        if (h[i]) atomicAdd(&tot[i], h[i]);
}

__global__ __launch_bounds__(1024) void kb_scan(const int* __restrict__ tot,
                                                int* __restrict__ start,
                                                int* __restrict__ cursor, int nbuck) {
    __shared__ int s[1024];
    int t = threadIdx.x;
    int v = (t < nbuck) ? tot[t] : 0;
    s[t] = v;
    __syncthreads();
    for (int d = 1; d < 1024; d <<= 1) {
        int add = (t >= d) ? s[t - d] : 0;
        __syncthreads();
        s[t] += add;
        __syncthreads();
    }
    if (t < nbuck) { start[t] = s[t] - v; cursor[t] = s[t] - v; }
    if (t == nbuck - 1) start[nbuck] = s[t];
}

__global__ __launch_bounds__(256) void kb_part(const int* __restrict__ row,
                                               const int* __restrict__ col,
                                               int e, int nbuck,
                                               int* __restrict__ cursor,
                                               int* __restrict__ part) {
    __shared__ int lcnt[1024];
    __shared__ int lbase[1024];
    int t = threadIdx.x;
    for (int i = t; i < 1024; i += 256) lcnt[i] = 0;
    __syncthreads();
    int base = blockIdx.x * CHUNK;
    int end = min(base + CHUNK, e);
    for (int i = base + t; i < end; i += 256)
        atomicAdd(&lcnt[col[i] >> 7], 1);
    __syncthreads();
    for (int i = t; i < nbuck; i += 256) {
        int c = lcnt[i];
        lbase[i] = c ? atomicAdd(&cursor[i], c) : 0;
    }
    __syncthreads();
    for (int i = t; i < 1024; i += 256) lcnt[i] = 0;
    __syncthreads();
    for (int i = base + t; i < end; i += 256) {
        int cl = col[i];
        int b = cl >> 7;
        int lp = atomicAdd(&lcnt[b], 1);
        part[lbase[b] + lp] = ((cl & 127) << 17) | row[i];
    }
}

__global__ __launch_bounds__(256) void kb_csr(const int* __restrict__ start,
                                              const int* __restrict__ part, int n,
                                              const float* __restrict__ x,
                                              float* __restrict__ dis,
                                              int* __restrict__ off,
                                              int* __restrict__ srow,
                                              __half* __restrict__ xs,
                                              __half* __restrict__ x0h) {
    __shared__ int cnt[128], excl[128], stmp[128];
    __shared__ float disl[128];
    int b = blockIdx.x;
    int t = threadIdx.x;
    int bstart = start[b], bend = start[b + 1];
    if (t < 128) cnt[t] = 0;
    __syncthreads();
    for (int i = bstart + t; i < bend; i += 256)
        atomicAdd(&cnt[part[i] >> 17], 1);
    __syncthreads();
    if (t < 128) stmp[t] = cnt[t];
    __syncthreads();
    for (int d = 1; d < 128; d <<= 1) {
        int add = (t < 128 && t >= d) ? stmp[t - d] : 0;
        __syncthreads();
        if (t < 128) stmp[t] += add;
        __syncthreads();
    }
    if (t < 128) {
        excl[t] = stmp[t] - cnt[t];
        int c = (b << 7) + t;
        float d = rsqrtf((float)cnt[t] + 1.0f);
        disl[t] = d;
        if (c < n) {
            off[c] = bstart + stmp[t];
            dis[c] = d;
        }
        cnt[t] = 0;
    }
    __syncthreads();
    for (int i = bstart + t; i < bend; i += 256) {
        int pk = part[i];
        int cl = pk >> 17;
        int lp = atomicAdd(&cnt[cl], 1);
        srow[bstart + excl[cl] + lp] = pk & 0x1FFFF;
    }
    int c0 = b << 7;
    for (int i = t; i < 128 * 64; i += 256) {
        int node = c0 + (i >> 6);
        if (node >= n) break;
        float xv = x[(size_t)node * 64 + (i & 63)];
        float d = disl[i >> 6];
        xs[(size_t)node * 64 + (i & 63)] = __float2half(d * xv);
        x0h[(size_t)node * 64 + (i & 63)] = __float2half(ALPHA * xv);
    }
}

// ================= weight prep =================

__global__ void k_prep(const float* __restrict__ gw, const float* __restrict__ w1,
                       __half* __restrict__ whT, __half* __restrict__ w1T, int L) {
    int i = blockIdx.x * blockDim.x + threadIdx.x;
    int tot = L * 4096;
    if (i < tot) {
        int l = i >> 12, r = i & 4095;
        int k = r >> 6, nf = r & 63;
        whT[(l << 12) + nf * 64 + k] = __float2half(gw[i]);
    } else if (i < tot + 1024) {
        int r = i - tot;
        int k = r >> 4, nf = r & 15;
        w1T[nf * 64 + k] = __float2half(w1[r]);
    }
}

// ================= fused GCN2 layer (MFMA, 4-deep gather MLP) =================

__global__ __launch_bounds__(256) void k_gcn2_fused(
    const int* __restrict__ srow, const int* __restrict__ endoff,
    const float* __restrict__ dis, const __half* __restrict__ hs_in,
    const __half* __restrict__ x0h, const __half* __restrict__ whT,
    __half* __restrict__ hs_out,           // null on last layer
    const __half* __restrict__ w1T,        // non-null on last layer
    __half* __restrict__ t16s, int n)
{
    __shared__ __half vs[32][72];
    __shared__ __half vs2[32][72];
    __shared__ float dcs[32];

    int t = threadIdx.x;
    int w = t >> 6;
    int lane = t & 63;
    int nb = blockIdx.x * 32;
    int m16 = lane & 15;
    int quad = lane >> 4;

    // B-fragments early: overlap the long gather latency
    f16x8 bf0 = *(const f16x8*)(whT + (size_t)(w * 16 + m16) * 64 + quad * 8);
    f16x8 bf1 = *(const f16x8*)(whT + (size_t)(w * 16 + m16) * 64 + 32 + quad * 8);

    // --- gather phase: lane = (node slot j, feature octet s) ---
    int j = lane >> 3;
    int s = lane & 7;
    int local = w * 8 + j;
    int c = nb + local;
    bool valid = c < n;
    int cc = valid ? c : 0;
    int start = (cc == 0) ? 0 : endoff[cc - 1];
    int end = valid ? endoff[cc] : 0;
    float dc = dis[cc];

    float a0, a1, a2, a3, a4, a5, a6, a7;
    float b0 = 0, b1 = 0, b2 = 0, b3 = 0, b4 = 0, b5 = 0, b6 = 0, b7 = 0;
    float c0 = 0, c1 = 0, c2 = 0, c3 = 0, c4 = 0, c5 = 0, c6 = 0, c7 = 0;
    float d0 = 0, d1 = 0, d2 = 0, d3 = 0, d4 = 0, d5 = 0, d6 = 0, d7 = 0;
    {   // self-loop term
        f16x8 q = *(const f16x8*)(hs_in + (size_t)cc * 64 + s * 8);
        a0 = (float)q[0]; a1 = (float)q[1]; a2 = (float)q[2]; a3 = (float)q[3];
        a4 = (float)q[4]; a5 = (float)q[5]; a6 = (float)q[6]; a7 = (float)q[7];
    }
    int e = start;
    for (; e + 4 <= end; e += 4) {
        int r0 = srow[e];
        int r1 = srow[e + 1];
        int r2 = srow[e + 2];
        int r3 = srow[e + 3];
        f16x8 q0 = *(const f16x8*)(hs_in + (size_t)r0 * 64 + s * 8);
        f16x8 q1 = *(const f16x8*)(hs_in + (size_t)r1 * 64 + s * 8);
        f16x8 q2 = *(const f16x8*)(hs_in + (size_t)r2 * 64 + s * 8);
        f16x8 q3 = *(const f16x8*)(hs_in + (size_t)r3 * 64 + s * 8);
        a0 += (float)q0[0]; a1 += (float)q0[1]; a2 += (float)q0[2]; a3 += (float)q0[3];
        a4 += (float)q0[4]; a5 += (float)q0[5]; a6 += (float)q0[6]; a7 += (float)q0[7];
        b0 += (float)q1[0]; b1 += (float)q1[1]; b2 += (float)q1[2]; b3 += (float)q1[3];
        b4 += (float)q1[4]; b5 += (float)q1[5]; b6 += (float)q1[6]; b7 += (float)q1[7];
        c0 += (float)q2[0]; c1 += (float)q2[1]; c2 += (float)q2[2]; c3 += (float)q2[3];
        c4 += (float)q2[4]; c5 += (float)q2[5]; c6 += (float)q2[6]; c7 += (float)q2[7];
        d0 += (float)q3[0]; d1 += (float)q3[1]; d2 += (float)q3[2]; d3 += (float)q3[3];
        d4 += (float)q3[4]; d5 += (float)q3[5]; d6 += (float)q3[6]; d7 += (float)q3[7];
    }
    for (; e < end; e++) {
        int r0 = srow[e];
        f16x8 q0 = *(const f16x8*)(hs_in + (size_t)r0 * 64 + s * 8);
        a0 += (float)q0[0]; a1 += (float)q0[1]; a2 += (float)q0[2]; a3 += (float)q0[3];
        a4 += (float)q0[4]; a5 += (float)q0[5]; a6 += (float)q0[6]; a7 += (float)q0[7];
    }
    a0 += b0 + c0 + d0; a1 += b1 + c1 + d1; a2 += b2 + c2 + d2; a3 += b3 + c3 + d3;
    a4 += b4 + c4 + d4; a5 += b5 + c5 + d5; a6 += b6 + c6 + d6; a7 += b7 + c7 + d7;

    if (valid) {
        float dc9 = (1.0f - ALPHA) * dc;
        const f16x8* xp = (const f16x8*)(x0h + (size_t)cc * 64 + s * 8);
        f16x8 xv = __builtin_nontemporal_load(xp);
        f16x8 vv;
        vv[0] = (_Float16)(dc9 * a0 + (float)xv[0]);
        vv[1] = (_Float16)(dc9 * a1 + (float)xv[1]);
        vv[2] = (_Float16)(dc9 * a2 + (float)xv[2]);
        vv[3] = (_Float16)(dc9 * a3 + (float)xv[3]);
        vv[4] = (_Float16)(dc9 * a4 + (float)xv[4]);
        vv[5] = (_Float16)(dc9 * a5 + (float)xv[5]);
        vv[6] = (_Float16)(dc9 * a6 + (float)xv[6]);
        vv[7] = (_Float16)(dc9 * a7 + (float)xv[7]);
        *(f16x8*)&vs[local][s * 8] = vv;
        if (s == 0) dcs[local] = dc;
    }
    __syncthreads();

    // --- MFMA phase ---
    bool last = (w1T != nullptr);
#pragma unroll
    for (int mt = 0; mt < 2; mt++) {
        f32x4 acc = {0.0f, 0.0f, 0.0f, 0.0f};
        f16x8 af0 = *(const f16x8*)&vs[mt * 16 + m16][quad * 8];
        f16x8 af1 = *(const f16x8*)&vs[mt * 16 + m16][32 + quad * 8];
        acc = __builtin_amdgcn_mfma_f32_16x16x32_f16(af0, bf0, acc, 0, 0, 0);
        acc = __builtin_amdgcn_mfma_f32_16x16x32_f16(af1, bf1, acc, 0, 0, 0);
        if (!last) {
#pragma unroll
            for (int r = 0; r < 4; r++) {
                int loc = mt * 16 + quad * 4 + r;
                int cn = nb + loc;
                if (cn < n) {
                    float h = fmaxf(acc[r], 0.0f);
                    nt_store_half(hs_out + (size_t)cn * 64 + w * 16 + m16, dcs[loc] * h);
                }
            }
        } else {
#pragma unroll
            for (int r = 0; r < 4; r++) {
                int loc = mt * 16 + quad * 4 + r;
                vs2[loc][w * 16 + m16] = __float2half(fmaxf(acc[r], 0.0f));
            }
        }
    }

    if (last) {
        __syncthreads();
        if (w < 2) {
            f16x8 w10 = *(const f16x8*)(w1T + (size_t)m16 * 64 + quad * 8);
            f16x8 w11 = *(const f16x8*)(w1T + (size_t)m16 * 64 + 32 + quad * 8);
            f16x8 af0 = *(const f16x8*)&vs2[w * 16 + m16][quad * 8];
            f16x8 af1 = *(const f16x8*)&vs2[w * 16 + m16][32 + quad * 8];
            f32x4 acc = {0.0f, 0.0f, 0.0f, 0.0f};
            acc = __builtin_amdgcn_mfma_f32_16x16x32_f16(af0, w10, acc, 0, 0, 0);
            acc = __builtin_amdgcn_mfma_f32_16x16x32_f16(af1, w11, acc, 0, 0, 0);
#pragma unroll
            for (int r = 0; r < 4; r++) {
                int loc = w * 16 + quad * 4 + r;
                int cn = nb + loc;
                if (cn < n)
                    nt_store_half(t16s + (size_t)cn * 16 + m16, dcs[loc] * acc[r]);
            }
        }
    }
}

// ================= fused prop16 + lin2 =================

__global__ __launch_bounds__(256) void k_prop16_lin2(
    const int* __restrict__ srow, const int* __restrict__ endoff,
    const float* __restrict__ dis, const __half* __restrict__ t16s,
    const float* __restrict__ b1, const float* __restrict__ w2,
    float* __restrict__ t1s, int n)
{
    int t = threadIdx.x;
    int w = t >> 6, lane = t & 63;
    int g = lane >> 2;
    int s = lane & 3;
    int c = blockIdx.x * 4 + w;
    if (c >= n) return;
    int start = (c == 0) ? 0 : endoff[c - 1];
    int end = endoff[c];
    float a0 = 0, a1 = 0, a2 = 0, a3 = 0;
    if (g == 0) {
        float2 q = *(const float2*)(t16s + (size_t)c * 16 + s * 4);
        float2 u;
        u = __half22float2(*(__half2*)&q.x); a0 = u.x; a1 = u.y;
        u = __half22float2(*(__half2*)&q.y); a2 = u.x; a3 = u.y;
    }
    for (int e = start + g; e < end; e += 16) {
        int r = srow[e];
        float2 q = *(const float2*)(t16s + (size_t)r * 16 + s * 4);
        float2 u;
        u = __half22float2(*(__half2*)&q.x); a0 += u.x; a1 += u.y;
        u = __half22float2(*(__half2*)&q.y); a2 += u.x; a3 += u.y;
    }
#pragma unroll
    for (int d = 4; d <= 32; d <<= 1) {
        a0 += __shfl_xor(a0, d, 64); a1 += __shfl_xor(a1, d, 64);
        a2 += __shfl_xor(a2, d, 64); a3 += __shfl_xor(a3, d, 64);
    }
    float dc = dis[c];
    float4 b = *(const float4*)(b1 + s * 4);
    float4 ww = *(const float4*)(w2 + s * 4);
    float partial = (dc * a0 + b.x) * ww.x + (dc * a1 + b.y) * ww.y +
                    (dc * a2 + b.z) * ww.z + (dc * a3 + b.w) * ww.w;
    partial += __shfl_xor(partial, 1, 64);
    partial += __shfl_xor(partial, 2, 64);
    if (lane == 0) t1s[c] = dc * partial;
}

// ================= prop1 + sigmoid =================

__global__ void k_prop1(const int* __restrict__ srow, const int* __restrict__ endoff,
                        const float* __restrict__ dis, const float* __restrict__ t1s,
                        const float* __restrict__ b2, float* __restrict__ out, int n) {
    int c = blockIdx.x * blockDim.x + threadIdx.x;
    if (c >= n) return;
    int start = (c == 0) ? 0 : endoff[c - 1];
    int end = endoff[c];
    float ssum = t1s[c];
    for (int e = start; e < end; e++) ssum += t1s[srow[e]];
    float v = dis[c] * ssum + b2[0];
    out[c] = 1.0f / (1.0f + expf(-v));
}

// ================= launch =================

static inline char* align16(char* p) {
    return (char*)(((uintptr_t)p + 15) & ~(uintptr_t)15);
}

extern "C" void kernel_launch(void* const* d_in, const int* in_sizes, int n_in,
                              void* d_out, int out_size, void* d_ws, size_t ws_size,
                              hipStream_t stream) {
    const float* x  = (const float*)d_in[0];
    const int*   ei = (const int*)d_in[1];
    const float* gw = (const float*)d_in[2];
    const float* w1 = (const float*)d_in[3];
    const float* b1 = (const float*)d_in[4];
    const float* w2 = (const float*)d_in[5];
    const float* b2 = (const float*)d_in[6];
    float* out = (float*)d_out;

    const int N = in_sizes[0] / 64;
    const int E = in_sizes[1] / 2;
    const int L = in_sizes[2] / (64 * 64);

    const int* row = ei;
    const int* col = ei + E;

    const int NB = (N + 127) >> 7;

    char* p = (char*)d_ws;
    int* off = (int*)p;            p = align16(p + (size_t)N * 4);
    float* dis = (float*)p;        p = align16(p + (size_t)N * 4);
    int* srow = (int*)p;           p = align16(p + (size_t)E * 4);
    int* bstart = (int*)p;         p = align16(p + (size_t)(NB + 1) * 4);
    int* bcur = (int*)p;           p = align16(p + (size_t)NB * 4);
    int* btot = (int*)p;           p = align16(p + (size_t)NB * 4);
    __half* whT = (__half*)p;      p = align16(p + (size_t)L * 4096 * 2);
    __half* w1T = (__half*)p;      p = align16(p + 1024 * 2);
    __half* hsA = (__half*)p;      p = align16(p + (size_t)N * 128);
    __half* hsB = (__half*)p;      p = align16(p + (size_t)N * 128);
    __half* x0h = (__half*)p;      p = align16(p + (size_t)N * 128);
    __half* t16s = (__half*)p;     p = align16(p + (size_t)N * 32);
    float* t1s = (float*)p;
    int* part = (int*)hsB;

    const int B = 256;
    int gN = (N + B - 1) / B;
    int gPart = (E + CHUNK - 1) / CHUNK;

    k_prep<<<(L * 4096 + 1024 + B - 1) / B, B, 0, stream>>>(gw, w1, whT, w1T, L);

    k_zero<<<(NB + B - 1) / B, B, 0, stream>>>(btot, NB);
    kb_hist<<<gPart, B, 0, stream>>>(col, E, NB, btot);
    kb_scan<<<1, 1024, 0, stream>>>(btot, bstart, bcur, NB);
    kb_part<<<gPart, B, 0, stream>>>(row, col, E, NB, bcur, part);
    kb_csr<<<NB, B, 0, stream>>>(bstart, part, N, x, dis, off, srow, hsA, x0h);

    __half* bufs[2] = {hsA, hsB};
    const __half* hin = hsA;
    for (int l = 0; l < L; l++) {
        bool lastl = (l == L - 1);
        __half* hout = lastl ? nullptr : bufs[(l + 1) & 1];
        k_gcn2_fused<<<(N + 31) / 32, B, 0, stream>>>(
            srow, off, dis, hin, x0h, whT + (size_t)l * 4096,
            hout, lastl ? w1T : nullptr, t16s, N);
        hin = hout;
    }

    k_prop16_lin2<<<(N + 3) / 4, B, 0, stream>>>(srow, off, dis, t16s, b1, w2, t1s, N);
    k_prop1<<<gN, B, 0, stream>>>(srow, off, dis, t1s, b2, out, N);
}